// Round 13
// baseline (18252.106 us; speedup 1.0000x reference)
//
#include <hip/hip_runtime.h>

#define T_STEPS 4096
#define HID 512
#define NLAYER 3
#define WGS_PER_LAYER 64
#define NWG (NLAYER * WGS_PER_LAYER)
#define NTHREADS 512
#define HCHUNK 8
#define ROWS_PER_WG 32
#define S_TOTAL (T_STEPS + NLAYER - 1)
#define HSEQ_ELEMS ((T_STEPS + 1) * HID)
#define HEAD_BLOCKS 256

__device__ __forceinline__ float sigmoid_fast(float x) {
    return 1.0f / (1.0f + __expf(-x));
}
__device__ __forceinline__ float tanh_fast(float x) {
    return 2.0f / (1.0f + __expf(-2.0f * x)) - 1.0f;
}
// XOR-swizzle on flat element index: spreads 128B-strided ds_read_b128 across
// banks (G4). Linear within aligned 4-element quads: swz(e+i)=swz(e)+i, i<4.
__device__ __forceinline__ int swz(int e) { return e ^ (((e >> 5) & 7) << 2); }

__device__ __forceinline__ float wload(int layer, const float* __restrict__ Wih,
                                       const float* __restrict__ Whh, int grow, int col) {
    if (col >= HID) return Whh[grow * HID + (col - HID)];
    if (layer == 0) return (col < 40) ? Wih[grow * 40 + col] : 0.0f;
    return Wih[grow * HID + col];
}

// Persistent systolic 3-layer LSTM scan, LDS-resident weights.
// 192 WGs: WG = layer*64 + w. Layer l at step s computes t = s - l.
// Each WG owns gate rows {g*512 + w*8 + hi : g<4, hi<8} (32 rows x 1024 cols,
// 128 KiB staged once into LDS). Thread (rg,cg): rows {rg, rg+16}, cols
// [cg*32, cg*32+32). v = [x_part | h_prev] restaged in LDS each step.
__global__ void __launch_bounds__(NTHREADS, 1)
lstm_scan(const float* __restrict__ x,
          const float* __restrict__ Wih0, const float* __restrict__ Whh0,
          const float* __restrict__ bih0, const float* __restrict__ bhh0,
          const float* __restrict__ Wih1, const float* __restrict__ Whh1,
          const float* __restrict__ bih1, const float* __restrict__ bhh1,
          const float* __restrict__ Wih2, const float* __restrict__ Whh2,
          const float* __restrict__ bih2, const float* __restrict__ bhh2,
          float* __restrict__ ws)
{
    const int wg    = blockIdx.x;
    const int layer = wg / WGS_PER_LAYER;
    const int w     = wg % WGS_PER_LAYER;
    const int tid   = threadIdx.x;
    const int rg    = tid >> 5;   // row-group 0..15 (rows rg and rg+16)
    const int cg    = tid & 31;   // col-group 0..31 (32 cols each)

    int*   flags = (int*)ws;                 // [0..256) ints
    float* hseq0 = ws + 256;
    float* hseq1 = hseq0 + HSEQ_ELEMS;
    float* hseq2 = hseq1 + HSEQ_ELEMS;
    float* hown        = (layer == 0) ? hseq0 : ((layer == 1) ? hseq1 : hseq2);
    const float* hprev = (layer == 0) ? hseq0 : ((layer == 1) ? hseq0 : hseq1);

    const float* Wih = (layer == 0) ? Wih0 : ((layer == 1) ? Wih1 : Wih2);
    const float* Whh = (layer == 0) ? Whh0 : ((layer == 1) ? Whh1 : Whh2);
    const float* bih = (layer == 0) ? bih0 : ((layer == 1) ? bih1 : bih2);
    const float* bhh = (layer == 0) ? bhh0 : ((layer == 1) ? bhh1 : bhh2);

    __shared__ float w_lds[ROWS_PER_WG * 1024];   // 128 KiB, swizzled cols
    __shared__ float v_lds[1024];                 // swizzled
    __shared__ float g_lds[ROWS_PER_WG];
    __shared__ float bias_lds[ROWS_PER_WG];

    // ---- stage stationary weights into LDS once (swizzled layout) ----
    #pragma unroll
    for (int half = 0; half < 2; ++half) {
        const int lr   = rg + half * 16;                          // 0..31
        const int grow = (lr >> 3) * HID + w * HCHUNK + (lr & 7); // gate row
        #pragma unroll
        for (int j = 0; j < 32; ++j) {
            const int col = cg * 32 + j;
            w_lds[lr * 1024 + swz(col)] = wload(layer, Wih, Whh, grow, col);
        }
    }
    if (tid < ROWS_PER_WG) {
        const int lr   = tid;
        const int grow = (lr >> 3) * HID + w * HCHUNK + (lr & 7);
        bias_lds[lr] = bih[grow] + bhh[grow];
    }
    __syncthreads();

    float c_state = 0.0f;   // cell state, meaningful for tid < 8

    for (int s = 0; s < S_TOTAL; ++s) {
        const int  t      = s - layer;
        const bool active = (t >= 0) && (t < T_STEPS);

        // ---- wait: own layer (h_own) + prev layer (h_prev) done with s-1 ----
        if (s > 0) {
            const int npoll = (layer == 0) ? 64 : 128;
            if (tid < npoll) {
                const int fidx = (layer == 0) ? tid : ((layer - 1) * 64 + tid);
                while (1) {
                    const int f = __hip_atomic_load(&flags[fidx], __ATOMIC_RELAXED,
                                                    __HIP_MEMORY_SCOPE_AGENT);
                    if (__all(f >= s)) break;
                }
            }
            asm volatile("" ::: "memory");   // no load hoisting above the poll
        }
        __syncthreads();

        // ---- stage v = [x_part | h_prev] into LDS (swizzled) ----
        if (active) {
            float xv, hv;
            if (layer == 0) {
                xv = (tid < 40) ? x[t * 40 + tid] : 0.0f;
            } else {
                xv = __hip_atomic_load(&hprev[(t + 1) * HID + tid], __ATOMIC_RELAXED,
                                       __HIP_MEMORY_SCOPE_AGENT);
            }
            hv = __hip_atomic_load(&hown[t * HID + tid], __ATOMIC_RELAXED,
                                   __HIP_MEMORY_SCOPE_AGENT);
            v_lds[swz(tid)]       = xv;
            v_lds[swz(HID + tid)] = hv;
        }
        __syncthreads();

        // ---- matvec: rows {rg, rg+16} x 32 cols, all operands from LDS ----
        if (active) {
            float acc0 = 0.f, acc1 = 0.f;
            const float* wrow0 = &w_lds[rg * 1024];
            const float* wrow1 = &w_lds[(rg + 16) * 1024];
            #pragma unroll
            for (int j = 0; j < 8; ++j) {
                const int e = (cg * 32 + j * 4) ^ ((cg & 7) << 2);   // == swz(col)
                const float4 vv = *reinterpret_cast<const float4*>(&v_lds[e]);
                const float4 w0 = *reinterpret_cast<const float4*>(&wrow0[e]);
                const float4 w1 = *reinterpret_cast<const float4*>(&wrow1[e]);
                acc0 = fmaf(w0.x, vv.x, acc0);
                acc0 = fmaf(w0.y, vv.y, acc0);
                acc0 = fmaf(w0.z, vv.z, acc0);
                acc0 = fmaf(w0.w, vv.w, acc0);
                acc1 = fmaf(w1.x, vv.x, acc1);
                acc1 = fmaf(w1.y, vv.y, acc1);
                acc1 = fmaf(w1.z, vv.z, acc1);
                acc1 = fmaf(w1.w, vv.w, acc1);
            }
            #pragma unroll
            for (int m = 1; m < 32; m <<= 1) {
                acc0 += __shfl_xor(acc0, m, 64);
                acc1 += __shfl_xor(acc1, m, 64);
            }
            if (cg == 0) {
                g_lds[rg]      = acc0;
                g_lds[rg + 16] = acc1;
            }
        }
        __syncthreads();

        // ---- gates, state update, publish h chunk (8 h-values per WG) ----
        if (active && tid < HCHUNK) {
            const float gi = sigmoid_fast(g_lds[tid]      + bias_lds[tid]);
            const float gf = sigmoid_fast(g_lds[8 + tid]  + bias_lds[8 + tid]);
            const float gc = tanh_fast   (g_lds[16 + tid] + bias_lds[16 + tid]);
            const float go = sigmoid_fast(g_lds[24 + tid] + bias_lds[24 + tid]);
            c_state = gf * c_state + gi * gc;
            const float h = go * tanh_fast(c_state);
            __hip_atomic_store(&hown[(t + 1) * HID + w * HCHUNK + tid], h,
                               __ATOMIC_RELAXED, __HIP_MEMORY_SCOPE_AGENT);
        }
        // release: own agent-scope h stores complete, then flag.
        asm volatile("s_waitcnt vmcnt(0)" ::: "memory");
        __syncthreads();
        if (tid == 0) {
            __hip_atomic_store(&flags[wg], s + 1, __ATOMIC_RELAXED,
                               __HIP_MEMORY_SCOPE_AGENT);
        }
    }
}

// Head: out[t] = softmax( tanh(h2[t] @ W1^T + b1) @ W2^T + b2 )
__global__ void __launch_bounds__(256)
head_kernel(const float* __restrict__ ws_ro,
            const float* __restrict__ W1, const float* __restrict__ b1,
            const float* __restrict__ W2, const float* __restrict__ b2,
            float* __restrict__ out)
{
    __shared__ float w1_lds[26 * 516];   // padded stride to break bank conflicts
    __shared__ float b1_lds[26];
    __shared__ float w2_lds[52];
    __shared__ float g_lds[32];
    const int tid = threadIdx.x;

    for (int i = tid; i < 26 * 512; i += 256)
        w1_lds[(i >> 9) * 516 + (i & 511)] = W1[i];
    if (tid < 26) b1_lds[tid] = b1[tid];
    if (tid < 52) w2_lds[tid] = W2[tid];
    __syncthreads();

    const float* h2 = ws_ro + 256 + 2 * HSEQ_ELEMS;   // layer-2 h sequence base
    const int r = tid >> 3;   // 0..31 (rows 0..25 used)
    const int c = tid & 7;    // 8 chunks of 64

    for (int t = blockIdx.x; t < T_STEPS; t += HEAD_BLOCKS) {
        float acc = 0.0f;
        if (r < 26) {
            const float* hrow = h2 + (t + 1) * HID + c * 64;
            const float* wrow = &w1_lds[r * 516 + c * 64];
            #pragma unroll
            for (int k = 0; k < 64; k += 4) {
                const float4 hv = *reinterpret_cast<const float4*>(&hrow[k]);
                const float4 wv = *reinterpret_cast<const float4*>(&wrow[k]);
                acc += hv.x * wv.x + hv.y * wv.y + hv.z * wv.z + hv.w * wv.w;
            }
        }
        acc += __shfl_xor(acc, 1, 64);
        acc += __shfl_xor(acc, 2, 64);
        acc += __shfl_xor(acc, 4, 64);
        if (r < 26 && c == 0) g_lds[r] = acc;
        __syncthreads();
        if (tid == 0) {
            float l0 = b2[0], l1 = b2[1];
            for (int j = 0; j < 26; ++j) {
                const float tj = tanhf(g_lds[j] + b1_lds[j]);
                l0 = fmaf(w2_lds[j],      tj, l0);
                l1 = fmaf(w2_lds[26 + j], tj, l1);
            }
            const float m  = fmaxf(l0, l1);
            const float e0 = __expf(l0 - m), e1 = __expf(l1 - m);
            const float inv = 1.0f / (e0 + e1);
            out[t * 2 + 0] = e0 * inv;
            out[t * 2 + 1] = e1 * inv;
        }
        __syncthreads();
    }
}

extern "C" void kernel_launch(void* const* d_in, const int* in_sizes, int n_in,
                              void* d_out, int out_size, void* d_ws, size_t ws_size,
                              hipStream_t stream)
{
    const float* x    = (const float*)d_in[0];
    const float* Wih0 = (const float*)d_in[1];
    const float* Whh0 = (const float*)d_in[2];
    const float* bih0 = (const float*)d_in[3];
    const float* bhh0 = (const float*)d_in[4];
    const float* Wih1 = (const float*)d_in[5];
    const float* Whh1 = (const float*)d_in[6];
    const float* bih1 = (const float*)d_in[7];
    const float* bhh1 = (const float*)d_in[8];
    const float* Wih2 = (const float*)d_in[9];
    const float* Whh2 = (const float*)d_in[10];
    const float* bih2 = (const float*)d_in[11];
    const float* bhh2 = (const float*)d_in[12];
    const float* W1   = (const float*)d_in[13];
    const float* b1   = (const float*)d_in[14];
    const float* W2   = (const float*)d_in[15];
    const float* b2   = (const float*)d_in[16];

    float* ws = (float*)d_ws;

    // ws layout (floats): [0..256) flags ; then 3 x HSEQ_ELEMS h-sequences
    // (row 0 of each sequence = h_{-1} = 0). Total ~24 MB.
    hipMemsetAsync(d_ws, 0, 1024, stream);                                               // flags
    hipMemsetAsync((char*)d_ws + 1024, 0, HID * sizeof(float), stream);                  // h0 row0
    hipMemsetAsync((char*)d_ws + 1024 + (size_t)HSEQ_ELEMS * 4, 0, HID * sizeof(float), stream);      // h1 row0
    hipMemsetAsync((char*)d_ws + 1024 + (size_t)2 * HSEQ_ELEMS * 4, 0, HID * sizeof(float), stream);  // h2 row0

    lstm_scan<<<NWG, NTHREADS, 0, stream>>>(x,
        Wih0, Whh0, bih0, bhh0,
        Wih1, Whh1, bih1, bhh1,
        Wih2, Whh2, bih2, bhh2, ws);

    head_kernel<<<HEAD_BLOCKS, 256, 0, stream>>>(ws, W1, b1, W2, b2, (float*)d_out);
}